// Round 3
// baseline (14920.505 us; speedup 1.0000x reference)
//
#include <hip/hip_runtime.h>
#include <hip/hip_fp16.h>

#define R       8192
#define C1      8213
#define C2      8192
#define CP      8224      // padded row stride in halves; row = 16448 B (16B aligned)
#define NCH     1028      // h8 chunks per row (CP/8)
#define NSPLIT  512       // blocks in fused pass
#define ROWS_PB 16        // R / NSPLIT
#define NG      8         // groups per block (2 rows each)

struct __align__(16) h8 { __half2 a, b, c, d; };

__device__ __forceinline__ void h8tof(const h8 k, float f[8]) {
    float2 x;
    x = __half22float2(k.a); f[0] = x.x; f[1] = x.y;
    x = __half22float2(k.b); f[2] = x.x; f[3] = x.y;
    x = __half22float2(k.c); f[4] = x.x; f[5] = x.y;
    x = __half22float2(k.d); f[6] = x.x; f[7] = x.y;
}

__device__ __forceinline__ float gm_label(float sc, int lab) {
    if (lab == 0) return fmaxf(-0.02f - sc, 0.0f) + fmaxf(sc, 0.0f);
    if (lab == 3) return fmaxf(0.09f + sc, 0.0f);
    return fmaxf(0.05f + sc, 0.0f) + fmaxf(-0.09f - sc, 0.0f); // labels 1|2
}

__device__ __forceinline__ float kval(float gm) {
    // K = exp(-M/REG), M = exp(-GM), REG = -0.2  ->  exp(5*exp(-GM)); fast hw exp
    return __expf(5.0f * __expf(-gm));
}

// ---- build kernels: K zero-padded to CP columns, h8 (16B) stores ----

__global__ __launch_bounds__(256) void build_k1(const float* __restrict__ dist,
                                                const int* __restrict__ lab,
                                                __half* __restrict__ K) {
    int row = blockIdx.y;
    int c = blockIdx.x * 256 + threadIdx.x;   // h8 chunk index
    if (c >= NCH) return;
    int j0 = c * 8;
    size_t ib = (size_t)row * C1;
    float d0 = dist[ib];
    float val[8];
#pragma unroll
    for (int k = 0; k < 8; ++k) {
        int j = j0 + k;
        val[k] = 0.0f;
        if (j < C1) {
            float g = gm_label(dist[ib + j] - d0, lab[ib + j]);
            val[k] = kval(g);
        }
    }
    h8 o;
    o.a = __floats2half2_rn(val[0], val[1]);
    o.b = __floats2half2_rn(val[2], val[3]);
    o.c = __floats2half2_rn(val[4], val[5]);
    o.d = __floats2half2_rn(val[6], val[7]);
    *reinterpret_cast<h8*>(K + (size_t)row * CP + j0) = o;
}

__global__ __launch_bounds__(256) void diag_k(const float* __restrict__ dist,
                                              float* __restrict__ dcol) {
    int j = blockIdx.x * 256 + threadIdx.x;
    if (j < R) dcol[j] = dist[(size_t)j * C1 + 21 + j];
}

__global__ __launch_bounds__(256) void build_k2(const float* __restrict__ dist,
                                                const float* __restrict__ dcol,
                                                __half* __restrict__ K) {
    int row = blockIdx.y;
    int c = blockIdx.x * 256 + threadIdx.x;
    if (c >= NCH) return;
    int j0 = c * 8;
    size_t ib = (size_t)row * C1 + 21;
    float val[8];
#pragma unroll
    for (int k = 0; k < 8; ++k) {
        int j = j0 + k;
        val[k] = 0.0f;
        if (j < C2) {
            float s = dist[ib + j] - dcol[j];
            float g = (j == row) ? 0.0f : fmaxf(0.09f + s, 0.0f);
            val[k] = kval(g);
        }
    }
    h8 o;
    o.a = __floats2half2_rn(val[0], val[1]);
    o.b = __floats2half2_rn(val[2], val[3]);
    o.c = __floats2half2_rn(val[4], val[5]);
    o.d = __floats2half2_rn(val[6], val[7]);
    *reinterpret_cast<h8*>(K + (size_t)row * CP + j0) = o;
}

// ---- initial column pass with uniform u = uval ----
__global__ __launch_bounds__(256) void col_partial0(const __half* __restrict__ K,
                                                    float* __restrict__ part, float uval) {
    int tx = threadIdx.x;
    bool tail = tx < 4;
    int r0 = blockIdx.x * ROWS_PB;
    float acc[4][8], acct[8];
#pragma unroll
    for (int i = 0; i < 4; ++i)
#pragma unroll
        for (int k = 0; k < 8; ++k) acc[i][k] = 0.0f;
#pragma unroll
    for (int k = 0; k < 8; ++k) acct[k] = 0.0f;
    for (int r = 0; r < ROWS_PB; ++r) {
        const h8* Ka = reinterpret_cast<const h8*>(K + (size_t)(r0 + r) * CP);
#pragma unroll
        for (int i = 0; i < 4; ++i) {
            float f[8]; h8tof(Ka[tx + i * 256], f);
#pragma unroll
            for (int k = 0; k < 8; ++k) acc[i][k] += f[k];
        }
        if (tail) {
            float f[8]; h8tof(Ka[1024 + tx], f);
#pragma unroll
            for (int k = 0; k < 8; ++k) acct[k] += f[k];
        }
    }
    float4* prow = reinterpret_cast<float4*>(part + (size_t)blockIdx.x * CP);
#pragma unroll
    for (int i = 0; i < 4; ++i) {
        prow[(tx + i * 256) * 2]     = make_float4(acc[i][0] * uval, acc[i][1] * uval,
                                                   acc[i][2] * uval, acc[i][3] * uval);
        prow[(tx + i * 256) * 2 + 1] = make_float4(acc[i][4] * uval, acc[i][5] * uval,
                                                   acc[i][6] * uval, acc[i][7] * uval);
    }
    if (tail) {
        prow[(1024 + tx) * 2]     = make_float4(acct[0] * uval, acct[1] * uval,
                                                acct[2] * uval, acct[3] * uval);
        prow[(1024 + tx) * 2 + 1] = make_float4(acct[4] * uval, acct[5] * uval,
                                                acct[6] * uval, acct[7] * uval);
    }
}

// ---- fused iteration: per 2-row group, compute u = aval/rowdot in-block, then
//      accumulate u*K into per-block column partials; K kept in regs, next group
//      prefetched across a RAW s_barrier (only lgkmcnt drained -> loads in flight) ----

#define LOADG(DST, DSTt, grp) do {                                             \
    int rr_ = r0 + (grp) * 2;                                                  \
    const h8* Ka_ = reinterpret_cast<const h8*>(K + (size_t)rr_ * CP);         \
    const h8* Kb_ = reinterpret_cast<const h8*>(K + (size_t)(rr_ + 1) * CP);   \
    _Pragma("unroll")                                                          \
    for (int i = 0; i < 4; ++i) {                                              \
        DST[0][i] = Ka_[tx + i * 256];                                         \
        DST[1][i] = Kb_[tx + i * 256];                                         \
    }                                                                          \
    if (tail) { DSTt[0] = Ka_[1024 + tx]; DSTt[1] = Kb_[1024 + tx]; }          \
} while (0)

#define GROUP(CUR, CURt, NXT, NXTt, g) do {                                    \
    float dA = 0.0f, dB = 0.0f;                                                \
    _Pragma("unroll")                                                          \
    for (int i = 0; i < 4; ++i) {                                              \
        float f_[8], h_[8];                                                    \
        h8tof(CUR[0][i], f_); h8tof(CUR[1][i], h_);                            \
        _Pragma("unroll")                                                      \
        for (int k = 0; k < 8; ++k) {                                          \
            dA = fmaf(f_[k], vv[i][k], dA);                                    \
            dB = fmaf(h_[k], vv[i][k], dB);                                    \
        }                                                                      \
    }                                                                          \
    if (tail) {                                                                \
        float f_[8], h_[8]; h8tof(CURt[0], f_); h8tof(CURt[1], h_);            \
        _Pragma("unroll")                                                      \
        for (int k = 0; k < 8; ++k) {                                          \
            dA = fmaf(f_[k], vt[k], dA);                                       \
            dB = fmaf(h_[k], vt[k], dB);                                       \
        }                                                                      \
    }                                                                          \
    _Pragma("unroll")                                                          \
    for (int off = 32; off; off >>= 1) {                                       \
        dA += __shfl_down(dA, off, 64);                                        \
        dB += __shfl_down(dB, off, 64);                                        \
    }                                                                          \
    if ((g) + 1 < NG) LOADG(NXT, NXTt, (g) + 1);                               \
    if (lane == 0) { rp[(g) & 1][0][wv] = dA; rp[(g) & 1][1][wv] = dB; }       \
    asm volatile("s_waitcnt lgkmcnt(0)" ::: "memory");                         \
    __builtin_amdgcn_s_barrier();                                              \
    asm volatile("" ::: "memory");                                             \
    float ug0 = aval / (rp[(g) & 1][0][0] + rp[(g) & 1][0][1] +                \
                        rp[(g) & 1][0][2] + rp[(g) & 1][0][3]);                \
    float ug1 = aval / (rp[(g) & 1][1][0] + rp[(g) & 1][1][1] +                \
                        rp[(g) & 1][1][2] + rp[(g) & 1][1][3]);                \
    _Pragma("unroll")                                                          \
    for (int i = 0; i < 4; ++i) {                                              \
        float f_[8], h_[8];                                                    \
        h8tof(CUR[0][i], f_); h8tof(CUR[1][i], h_);                            \
        _Pragma("unroll")                                                      \
        for (int k = 0; k < 8; ++k)                                            \
            acc[i][k] = fmaf(ug0, f_[k], fmaf(ug1, h_[k], acc[i][k]));         \
    }                                                                          \
    if (tail) {                                                                \
        float f_[8], h_[8]; h8tof(CURt[0], f_); h8tof(CURt[1], h_);            \
        _Pragma("unroll")                                                      \
        for (int k = 0; k < 8; ++k)                                            \
            acct[k] = fmaf(ug0, f_[k], fmaf(ug1, h_[k], acct[k]));             \
    }                                                                          \
} while (0)

__global__ __launch_bounds__(256, 2) void fused_iter(const __half* __restrict__ K,
                                                     const float* __restrict__ v,
                                                     float* __restrict__ part,
                                                     float aval) {
    __shared__ float rp[2][2][4];
    int tx = threadIdx.x;
    int lane = tx & 63, wv = tx >> 6;
    bool tail = tx < 4;
    int r0 = blockIdx.x * ROWS_PB;

    const float4* v4 = reinterpret_cast<const float4*>(v);
    float vv[4][8], vt[8];
#pragma unroll
    for (int i = 0; i < 4; ++i) {
        float4 p = v4[(tx + i * 256) * 2];
        float4 q = v4[(tx + i * 256) * 2 + 1];
        vv[i][0] = p.x; vv[i][1] = p.y; vv[i][2] = p.z; vv[i][3] = p.w;
        vv[i][4] = q.x; vv[i][5] = q.y; vv[i][6] = q.z; vv[i][7] = q.w;
    }
#pragma unroll
    for (int k = 0; k < 8; ++k) vt[k] = 0.0f;
    if (tail) {
        float4 p = v4[(1024 + tx) * 2], q = v4[(1024 + tx) * 2 + 1];
        vt[0] = p.x; vt[1] = p.y; vt[2] = p.z; vt[3] = p.w;
        vt[4] = q.x; vt[5] = q.y; vt[6] = q.z; vt[7] = q.w;
    }

    float acc[4][8], acct[8];
#pragma unroll
    for (int i = 0; i < 4; ++i)
#pragma unroll
        for (int k = 0; k < 8; ++k) acc[i][k] = 0.0f;
#pragma unroll
    for (int k = 0; k < 8; ++k) acct[k] = 0.0f;

    h8 chA[2][4], chB[2][4], chAt[2], chBt[2];
    LOADG(chA, chAt, 0);
#pragma unroll
    for (int g = 0; g < NG; g += 2) {
        GROUP(chA, chAt, chB, chBt, g);
        GROUP(chB, chBt, chA, chAt, g + 1);
    }

    float4* prow = reinterpret_cast<float4*>(part + (size_t)blockIdx.x * CP);
#pragma unroll
    for (int i = 0; i < 4; ++i) {
        prow[(tx + i * 256) * 2]     = make_float4(acc[i][0], acc[i][1], acc[i][2], acc[i][3]);
        prow[(tx + i * 256) * 2 + 1] = make_float4(acc[i][4], acc[i][5], acc[i][6], acc[i][7]);
    }
    if (tail) {
        prow[(1024 + tx) * 2]     = make_float4(acct[0], acct[1], acct[2], acct[3]);
        prow[(1024 + tx) * 2 + 1] = make_float4(acct[4], acct[5], acct[6], acct[7]);
    }
}

// ---- v[j] = bval / sum_s part[s][j]; 64 cols x 4 split-quarters per block ----
__global__ __launch_bounds__(256) void col_reduce(const float* __restrict__ part,
                                                  float* __restrict__ v, int C, float bval) {
    __shared__ float sb[4][64];
    int tx = threadIdx.x;
    int c = tx & 63, q = tx >> 6;
    int j = blockIdx.x * 64 + c;
    float s = 0.0f;
    if (j < CP) {
        const float* p = part + (size_t)q * 128 * CP + j;
        for (int k = 0; k < 128; ++k) s += p[(size_t)k * CP];
    }
    sb[q][c] = s;
    __syncthreads();
    if (tx < 64) {
        int jj = blockIdx.x * 64 + tx;
        if (jj < CP) {
            float t = sb[0][tx] + sb[1][tx] + sb[2][tx] + sb[3][tx];
            v[jj] = (jj < C) ? bval / t : 0.0f;
        }
    }
}

// ---- loss reductions ----

__device__ __forceinline__ float2 block_reduce_2(float x, float y, float* sb) {
#pragma unroll
    for (int off = 32; off; off >>= 1) {
        x += __shfl_down(x, off, 64);
        y += __shfl_down(y, off, 64);
    }
    if ((threadIdx.x & 63) == 0) {
        int w = threadIdx.x >> 6;
        sb[w] = x; sb[4 + w] = y;
    }
    __syncthreads();
    float2 r;
    r.x = sb[0] + sb[1] + sb[2] + sb[3];
    r.y = sb[4] + sb[5] + sb[6] + sb[7];
    __syncthreads();
    return r;
}

__global__ __launch_bounds__(256) void loss1_k(const __half* __restrict__ K,
                                               const float* __restrict__ v,
                                               const float* __restrict__ dist,
                                               const int* __restrict__ lab,
                                               float* __restrict__ ratio) {
    __shared__ float sb[8];
    int i = blockIdx.x;
    size_t ib = (size_t)i * C1;
    float d0 = dist[ib];
    const __half* Kr = K + (size_t)i * CP;
    float num = 0, den = 0;
    for (int j = threadIdx.x; j < C1; j += 256) {
        float kv = __half2float(Kr[j]) * v[j];
        float g = gm_label(dist[ib + j] - d0, lab[ib + j]);
        den += kv;
        num = fmaf(g, kv, num);
    }
    float2 r = block_reduce_2(num, den, sb);
    if (threadIdx.x == 0) ratio[i] = r.x / r.y;
}

__global__ __launch_bounds__(256) void loss2_k(const __half* __restrict__ K,
                                               const float* __restrict__ v,
                                               const float* __restrict__ dist,
                                               const float* __restrict__ dcol,
                                               float* __restrict__ ratio) {
    __shared__ float sb[8];
    int i = blockIdx.x;
    const __half* Kr = K + (size_t)i * CP;
    const float* Dr = dist + (size_t)i * C1 + 21;
    float num = 0, den = 0;
    for (int j = threadIdx.x; j < C2; j += 256) {
        if (j == i) continue;
        float kv = __half2float(Kr[j]) * v[j];
        float h = fmaxf(0.09f + Dr[j] - dcol[j], 0.0f);
        den += kv;
        num = fmaf(h, kv, num);
    }
    float2 r = block_reduce_2(num, den, sb);
    if (threadIdx.x == 0) ratio[i] = r.x / r.y;
}

__global__ __launch_bounds__(256) void final_k(const float* __restrict__ r1,
                                               const float* __restrict__ r2,
                                               float* __restrict__ out) {
    __shared__ float sb[8];
    float s1 = 0, s2 = 0;
    for (int i = threadIdx.x; i < R; i += 256) { s1 += r1[i]; s2 += r2[i]; }
    float2 t = block_reduce_2(s1, s2, sb);
    if (threadIdx.x == 0)
        out[0] = t.x / ((float)R * (float)C1) + t.y / ((float)R * (float)C2);
}

static void run_phase(const __half* K, float* v, float* part, int C, hipStream_t stream) {
    float aval = 1.0f / (float)R;
    float bval = 1.0f / (float)C;
    col_partial0<<<dim3(NSPLIT), 256, 0, stream>>>(K, part, aval);
    int gcr = (CP + 63) / 64;   // 129
    for (int t = 0; t < 50; ++t) {
        col_reduce<<<dim3(gcr), 256, 0, stream>>>(part, v, C, bval);
        if (t < 49)
            fused_iter<<<dim3(NSPLIT), 256, 0, stream>>>(K, v, part, aval);
    }
}

extern "C" void kernel_launch(void* const* d_in, const int* in_sizes, int n_in,
                              void* d_out, int out_size, void* d_ws, size_t ws_size,
                              hipStream_t stream) {
    const float* dist = (const float*)d_in[0];
    const int* lab = (const int*)d_in[1];
    float* out = (float*)d_out;
    char* ws = (char*)d_ws;

    size_t need = (size_t)R * CP * sizeof(__half)        // K
                + (size_t)NSPLIT * CP * sizeof(float)    // part
                + (size_t)CP * sizeof(float)             // v
                + 3 * (size_t)R * sizeof(float);         // dcol, rat1, rat2
    if (ws_size < need) return;

    size_t off = 0;
    __half* K = (__half*)(ws + off);   off += (size_t)R * CP * sizeof(__half);
    float* part = (float*)(ws + off);  off += (size_t)NSPLIT * CP * sizeof(float);
    float* v = (float*)(ws + off);     off += (size_t)CP * sizeof(float);
    float* dcol = (float*)(ws + off);  off += (size_t)R * sizeof(float);
    float* rat1 = (float*)(ws + off);  off += (size_t)R * sizeof(float);
    float* rat2 = (float*)(ws + off);  off += (size_t)R * sizeof(float);

    int gb = (NCH + 255) / 256;  // 5

    // ---- phase 1 ----
    build_k1<<<dim3(gb, R), 256, 0, stream>>>(dist, lab, K);
    run_phase(K, v, part, C1, stream);
    loss1_k<<<dim3(R), 256, 0, stream>>>(K, v, dist, lab, rat1);

    // ---- phase 2 (reuses K buffer) ----
    diag_k<<<dim3((R + 255) / 256), 256, 0, stream>>>(dist, dcol);
    build_k2<<<dim3(gb, R), 256, 0, stream>>>(dist, dcol, K);
    run_phase(K, v, part, C2, stream);
    loss2_k<<<dim3(R), 256, 0, stream>>>(K, v, dist, dcol, rat2);

    final_k<<<dim3(1), 256, 0, stream>>>(rat1, rat2, out);
}

// Round 4
// 5367.172 us; speedup vs baseline: 2.7800x; 2.7800x over previous
//
#include <hip/hip_runtime.h>
#include <hip/hip_fp16.h>

#define R       8192
#define C1      8213
#define C2      8192
#define CP      8216      // padded row stride (halves / floats); 8216*2B = 16432B, 16B-aligned
#define NH8     1027      // h8 chunks per row (CP/8), exact
#define NSPLIT  128       // row splits for column pass
#define RPS     64        // rows per split (R / NSPLIT)

struct __align__(16) h8 { __half2 a, b, c, d; };

__device__ __forceinline__ void h8tof(const h8 k, float f[8]) {
    float2 x;
    x = __half22float2(k.a); f[0] = x.x; f[1] = x.y;
    x = __half22float2(k.b); f[2] = x.x; f[3] = x.y;
    x = __half22float2(k.c); f[4] = x.x; f[5] = x.y;
    x = __half22float2(k.d); f[6] = x.x; f[7] = x.y;
}

__device__ __forceinline__ float gm_label(float sc, int lab) {
    if (lab == 0) return fmaxf(-0.02f - sc, 0.0f) + fmaxf(sc, 0.0f);
    if (lab == 3) return fmaxf(0.09f + sc, 0.0f);
    return fmaxf(0.05f + sc, 0.0f) + fmaxf(-0.09f - sc, 0.0f); // labels 1|2
}

__device__ __forceinline__ float kval(float gm) {
    // K = exp(-M/REG), M = exp(-GM), REG = -0.2  ->  exp(5*exp(-GM)); hw exp
    return __expf(5.0f * __expf(-gm));
}

// ---- build kernels (R2-proven layout: 4 elems/thread, stride-16B, h4 stores) ----

__global__ __launch_bounds__(256) void build_k1(const float* __restrict__ dist,
                                                const int* __restrict__ lab,
                                                __half* __restrict__ K) {
    int row = blockIdx.y;
    int j0 = (blockIdx.x * 256 + threadIdx.x) * 4;
    if (j0 >= CP) return;
    size_t ib = (size_t)row * C1;
    float d0 = dist[ib];
    float val[4];
#pragma unroll
    for (int k = 0; k < 4; ++k) {
        int j = j0 + k;
        val[k] = 0.0f;
        if (j < C1) {
            float g = gm_label(dist[ib + j] - d0, lab[ib + j]);
            val[k] = kval(g);
        }
    }
    __half2* o = reinterpret_cast<__half2*>(K + (size_t)row * CP + j0);
    o[0] = __floats2half2_rn(val[0], val[1]);
    o[1] = __floats2half2_rn(val[2], val[3]);
}

__global__ __launch_bounds__(256) void diag_k(const float* __restrict__ dist,
                                              float* __restrict__ dcol) {
    int j = blockIdx.x * 256 + threadIdx.x;
    if (j < R) dcol[j] = dist[(size_t)j * C1 + 21 + j];
}

__global__ __launch_bounds__(256) void build_k2(const float* __restrict__ dist,
                                                const float* __restrict__ dcol,
                                                __half* __restrict__ K) {
    int row = blockIdx.y;
    int j0 = (blockIdx.x * 256 + threadIdx.x) * 4;
    if (j0 >= CP) return;
    size_t ib = (size_t)row * C1 + 21;
    float val[4];
#pragma unroll
    for (int k = 0; k < 4; ++k) {
        int j = j0 + k;
        val[k] = 0.0f;
        if (j < C2) {
            float s = dist[ib + j] - dcol[j];
            float g = (j == row) ? 0.0f : fmaxf(0.09f + s, 0.0f);
            val[k] = kval(g);
        }
    }
    __half2* o = reinterpret_cast<__half2*>(K + (size_t)row * CP + j0);
    o[0] = __floats2half2_rn(val[0], val[1]);
    o[1] = __floats2half2_rn(val[2], val[3]);
}

__global__ __launch_bounds__(256) void fill_f(float* __restrict__ p, int n, float val) {
    int i = blockIdx.x * 256 + threadIdx.x;
    if (i < n) p[i] = val;
}

// ---- column pass: part[s][j] = sum_{r in split s} K[r][j] * u[r]
//      grid (5 col-strips, 128 row-splits); thread owns 8 cols (one h8), 64 rows ----
__global__ __launch_bounds__(256) void col_partial(const __half* __restrict__ K,
                                                   const float* __restrict__ u,
                                                   float* __restrict__ part) {
    __shared__ float us[RPS];
    int tx = threadIdx.x;
    int sp = blockIdx.y;
    int r0 = sp * RPS;
    if (tx < RPS) us[tx] = u[r0 + tx];
    __syncthreads();
    int c = blockIdx.x * 256 + tx;          // h8 chunk index
    if (c >= NH8) return;
    const h8* Kp = reinterpret_cast<const h8*>(K + (size_t)r0 * CP) + c;
    float acc[8];
#pragma unroll
    for (int k = 0; k < 8; ++k) acc[k] = 0.0f;
    for (int r = 0; r < RPS; ++r) {
        float f[8];
        h8tof(Kp[(size_t)r * NH8], f);
        float uu = us[r];
#pragma unroll
        for (int k = 0; k < 8; ++k) acc[k] = fmaf(f[k], uu, acc[k]);
    }
    float4* prow = reinterpret_cast<float4*>(part + (size_t)sp * CP + c * 8);
    prow[0] = make_float4(acc[0], acc[1], acc[2], acc[3]);
    prow[1] = make_float4(acc[4], acc[5], acc[6], acc[7]);
}

// ---- v[j] = bval / sum_s part[s][j]; 64 cols x 4 split-quarters per block ----
__global__ __launch_bounds__(256) void col_reduce(const float* __restrict__ part,
                                                  float* __restrict__ v, int C, float bval) {
    __shared__ float sb[4][64];
    int tx = threadIdx.x;
    int c = tx & 63, q = tx >> 6;
    int j = blockIdx.x * 64 + c;
    float s = 0.0f;
    if (j < CP) {
        const float* p = part + (size_t)q * (NSPLIT / 4) * CP + j;
        for (int k = 0; k < NSPLIT / 4; ++k) s += p[(size_t)k * CP];
    }
    sb[q][c] = s;
    __syncthreads();
    if (tx < 64) {
        int jj = blockIdx.x * 64 + tx;
        if (jj < CP) {
            float t = sb[0][tx] + sb[1][tx] + sb[2][tx] + sb[3][tx];
            v[jj] = (jj < C) ? bval / t : 0.0f;
        }
    }
}

// ---- row pass: u[i] = aval / sum_j K[i][j]*v[j]
//      v staged in LDS once; each wave independently owns 4 rows (no inner barriers) ----
__global__ __launch_bounds__(256) void row_pass(const __half* __restrict__ K,
                                                const float* __restrict__ v,
                                                float* __restrict__ u, float aval) {
    __shared__ float vs[CP];
    int tx = threadIdx.x;
    {
        const float4* v4 = reinterpret_cast<const float4*>(v);
        float4* s4 = reinterpret_cast<float4*>(vs);
        for (int i = tx; i < CP / 4; i += 256) s4[i] = v4[i];
    }
    __syncthreads();
    int lane = tx & 63, wv = tx >> 6;
    int rowbase = blockIdx.x * 16 + wv * 4;
#pragma unroll
    for (int rr = 0; rr < 4; ++rr) {
        int row = rowbase + rr;
        const h8* K8 = reinterpret_cast<const h8*>(K + (size_t)row * CP);
        float dot = 0.0f;
#pragma unroll
        for (int s = 0; s < 16; ++s) {
            int ch = lane + s * 64;
            float f[8];
            h8tof(K8[ch], f);
            const float* vp = vs + ch * 8;
#pragma unroll
            for (int k = 0; k < 8; ++k) dot = fmaf(f[k], vp[k], dot);
        }
        if (lane < 3) {   // tail chunks 1024..1026
            int ch = 1024 + lane;
            float f[8];
            h8tof(K8[ch], f);
            const float* vp = vs + ch * 8;
#pragma unroll
            for (int k = 0; k < 8; ++k) dot = fmaf(f[k], vp[k], dot);
        }
#pragma unroll
        for (int off = 32; off; off >>= 1) dot += __shfl_down(dot, off, 64);
        if (lane == 0) u[row] = aval / dot;
    }
}

// ---- loss reductions ----

__device__ __forceinline__ float2 block_reduce_2(float x, float y, float* sb) {
#pragma unroll
    for (int off = 32; off; off >>= 1) {
        x += __shfl_down(x, off, 64);
        y += __shfl_down(y, off, 64);
    }
    if ((threadIdx.x & 63) == 0) {
        int w = threadIdx.x >> 6;
        sb[w] = x; sb[4 + w] = y;
    }
    __syncthreads();
    float2 r;
    r.x = sb[0] + sb[1] + sb[2] + sb[3];
    r.y = sb[4] + sb[5] + sb[6] + sb[7];
    __syncthreads();
    return r;
}

__global__ __launch_bounds__(256) void loss1_k(const __half* __restrict__ K,
                                               const float* __restrict__ v,
                                               const float* __restrict__ dist,
                                               const int* __restrict__ lab,
                                               float* __restrict__ ratio) {
    __shared__ float sb[8];
    int i = blockIdx.x;
    size_t ib = (size_t)i * C1;
    float d0 = dist[ib];
    const __half* Kr = K + (size_t)i * CP;
    float num = 0, den = 0;
    for (int j = threadIdx.x; j < C1; j += 256) {
        float kv = __half2float(Kr[j]) * v[j];
        float g = gm_label(dist[ib + j] - d0, lab[ib + j]);
        den += kv;
        num = fmaf(g, kv, num);
    }
    float2 r = block_reduce_2(num, den, sb);
    if (threadIdx.x == 0) ratio[i] = r.x / r.y;
}

__global__ __launch_bounds__(256) void loss2_k(const __half* __restrict__ K,
                                               const float* __restrict__ v,
                                               const float* __restrict__ dist,
                                               const float* __restrict__ dcol,
                                               float* __restrict__ ratio) {
    __shared__ float sb[8];
    int i = blockIdx.x;
    const __half* Kr = K + (size_t)i * CP;
    const float* Dr = dist + (size_t)i * C1 + 21;
    float num = 0, den = 0;
    for (int j = threadIdx.x; j < C2; j += 256) {
        if (j == i) continue;
        float kv = __half2float(Kr[j]) * v[j];
        float h = fmaxf(0.09f + Dr[j] - dcol[j], 0.0f);
        den += kv;
        num = fmaf(h, kv, num);
    }
    float2 r = block_reduce_2(num, den, sb);
    if (threadIdx.x == 0) ratio[i] = r.x / r.y;
}

__global__ __launch_bounds__(256) void final_k(const float* __restrict__ r1,
                                               const float* __restrict__ r2,
                                               float* __restrict__ out) {
    __shared__ float sb[8];
    float s1 = 0, s2 = 0;
    for (int i = threadIdx.x; i < R; i += 256) { s1 += r1[i]; s2 += r2[i]; }
    float2 t = block_reduce_2(s1, s2, sb);
    if (threadIdx.x == 0)
        out[0] = t.x / ((float)R * (float)C1) + t.y / ((float)R * (float)C2);
}

static void run_phase(const __half* K, float* u, float* v, float* part, int C,
                      hipStream_t stream) {
    float aval = 1.0f / (float)R;
    float bval = 1.0f / (float)C;
    fill_f<<<dim3(R / 256), 256, 0, stream>>>(u, R, aval);
    int gx = (NH8 + 255) / 256;   // 5 column strips
    int gcr = (CP + 63) / 64;     // 129
    for (int t = 0; t < 50; ++t) {
        col_partial<<<dim3(gx, NSPLIT), 256, 0, stream>>>(K, u, part);
        col_reduce<<<dim3(gcr), 256, 0, stream>>>(part, v, C, bval);
        if (t < 49)
            row_pass<<<dim3(R / 16), 256, 0, stream>>>(K, v, u, aval);
    }
}

extern "C" void kernel_launch(void* const* d_in, const int* in_sizes, int n_in,
                              void* d_out, int out_size, void* d_ws, size_t ws_size,
                              hipStream_t stream) {
    const float* dist = (const float*)d_in[0];
    const int* lab = (const int*)d_in[1];
    float* out = (float*)d_out;
    char* ws = (char*)d_ws;

    size_t need = (size_t)R * CP * sizeof(__half)        // K
                + (size_t)NSPLIT * CP * sizeof(float)    // part
                + (size_t)CP * sizeof(float)             // v
                + 4 * (size_t)R * sizeof(float);         // u, dcol, rat1, rat2
    if (ws_size < need) return;

    size_t off = 0;
    __half* K = (__half*)(ws + off);   off += (size_t)R * CP * sizeof(__half);
    float* part = (float*)(ws + off);  off += (size_t)NSPLIT * CP * sizeof(float);
    float* v = (float*)(ws + off);     off += (size_t)CP * sizeof(float);
    float* u = (float*)(ws + off);     off += (size_t)R * sizeof(float);
    float* dcol = (float*)(ws + off);  off += (size_t)R * sizeof(float);
    float* rat1 = (float*)(ws + off);  off += (size_t)R * sizeof(float);
    float* rat2 = (float*)(ws + off);  off += (size_t)R * sizeof(float);

    int gb = (CP / 4 + 255) / 256;  // 9 blocks per row

    // ---- phase 1 ----
    build_k1<<<dim3(gb, R), 256, 0, stream>>>(dist, lab, K);
    run_phase(K, u, v, part, C1, stream);
    loss1_k<<<dim3(R), 256, 0, stream>>>(K, v, dist, lab, rat1);

    // ---- phase 2 (reuses K buffer) ----
    diag_k<<<dim3(R / 256), 256, 0, stream>>>(dist, dcol);
    build_k2<<<dim3(gb, R), 256, 0, stream>>>(dist, dcol, K);
    run_phase(K, u, v, part, C2, stream);
    loss2_k<<<dim3(R), 256, 0, stream>>>(K, v, dist, dcol, rat2);

    final_k<<<dim3(1), 256, 0, stream>>>(rat1, rat2, out);
}